// Round 1
// baseline (1386.108 us; speedup 1.0000x reference)
//
#include <hip/hip_runtime.h>
#include <math.h>

#define T_LEN 1024
#define B_SZ  256
#define I_SZ  128
#define H_SZ  64
#define G_SZ  256   // 4*H

// ---------------------------------------------------------------------------
// Kernel 1: forward-direction LSTM scan. One block per batch element (256
// blocks = 256 CUs), 256 threads; thread j owns gate row j (0..255).
// Weights held in registers (W_ih row: 128 f32, W_hh row: 64 f32).
// x_t staged in LDS (double buffered); h exchanged via LDS each step.
// Writes final h [B,64] to workspace.
// ---------------------------------------------------------------------------
__global__ __launch_bounds__(256, 1) void lstm_fwd_scan(
    const float* __restrict__ x,      // [T,B,I]
    const float* __restrict__ W_ih,   // [256,128]
    const float* __restrict__ W_hh,   // [256,64]
    const float* __restrict__ bias,   // [256]
    float* __restrict__ h_out)        // [B,64]
{
    const int b = blockIdx.x;
    const int j = threadIdx.x;

    // --- load weight rows into registers (one-time; L2-cached across blocks)
    float wih[I_SZ];
    float whh[H_SZ];
#pragma unroll
    for (int k = 0; k < I_SZ / 4; ++k) {
        float4 v = *reinterpret_cast<const float4*>(&W_ih[j * I_SZ + 4 * k]);
        wih[4 * k + 0] = v.x; wih[4 * k + 1] = v.y;
        wih[4 * k + 2] = v.z; wih[4 * k + 3] = v.w;
    }
#pragma unroll
    for (int k = 0; k < H_SZ / 4; ++k) {
        float4 v = *reinterpret_cast<const float4*>(&W_hh[j * H_SZ + 4 * k]);
        whh[4 * k + 0] = v.x; whh[4 * k + 1] = v.y;
        whh[4 * k + 2] = v.z; whh[4 * k + 3] = v.w;
    }
    const float bj = bias[j];

    __shared__ float xs[2][I_SZ];
    __shared__ float hs[H_SZ];
    __shared__ float gs[G_SZ];

    float c = 0.0f;                     // cell state: thread j<64 holds c[j]
    if (j < H_SZ) hs[j] = 0.0f;
    if (j < I_SZ) xs[0][j] = x[(size_t)b * I_SZ + j];   // t = 0
    __syncthreads();

    for (int t = 0; t < T_LEN; ++t) {
        const int cur = t & 1;
        // prefetch x[t+1] into the other buffer (safe: last iter's reads of
        // that buffer are fenced by the two barriers below)
        if (t + 1 < T_LEN && j < I_SZ)
            xs[cur ^ 1][j] = x[(size_t)(t + 1) * B_SZ * I_SZ + (size_t)b * I_SZ + j];

        // gate pre-activation: dot(x_t, wih_row) + dot(h, whh_row) + b
        float acc = bj;
#pragma unroll
        for (int k = 0; k < I_SZ; k += 4) {
            float4 xv = *reinterpret_cast<const float4*>(&xs[cur][k]);  // broadcast
            acc += xv.x * wih[k + 0] + xv.y * wih[k + 1]
                 + xv.z * wih[k + 2] + xv.w * wih[k + 3];
        }
#pragma unroll
        for (int m = 0; m < H_SZ; m += 4) {
            float4 hv = *reinterpret_cast<const float4*>(&hs[m]);       // broadcast
            acc += hv.x * whh[m + 0] + hv.y * whh[m + 1]
                 + hv.z * whh[m + 2] + hv.w * whh[m + 3];
        }

        // activation: gate id = j>>6 ; order i,f,g,o ; g -> tanh, rest sigmoid
        const int gate = j >> 6;
        float a;
        if (gate == 2) a = tanhf(acc);
        else           a = 1.0f / (1.0f + expf(-acc));
        gs[j] = a;
        __syncthreads();

        if (j < H_SZ) {
            const float ig = gs[j];
            const float fg = gs[H_SZ + j];
            const float gg = gs[2 * H_SZ + j];
            const float og = gs[3 * H_SZ + j];
            c = fg * c + ig * gg;
            hs[j] = og * tanhf(c);
        }
        __syncthreads();
    }

    if (j < H_SZ) h_out[b * H_SZ + j] = hs[j];
}

// ---------------------------------------------------------------------------
// Kernel 2: reverse-direction single cell (zero initial state) + MLP head.
// One block per batch element, 256 threads.
//   h_bwd: gates = x[-1] @ W_ih_r^T + b_r ;  c = i*g ; h = o*tanh(c)
//   h_cat = [h_fwd, h_bwd] ; fc1(relu) -> fc2(relu) -> fc3
// ---------------------------------------------------------------------------
__global__ __launch_bounds__(256, 1) void lstm_tail(
    const float* __restrict__ x_last,  // [B,I] (= &x[(T-1)*B*I])
    const float* __restrict__ W_ih_r,  // [256,128]
    const float* __restrict__ b_r,     // [256]
    const float* __restrict__ h_fwd,   // [B,64]
    const float* __restrict__ fc1_w,   // [64,128]
    const float* __restrict__ fc1_b,   // [64]
    const float* __restrict__ fc2_w,   // [32,64]
    const float* __restrict__ fc2_b,   // [32]
    const float* __restrict__ fc3_w,   // [10,32]
    const float* __restrict__ fc3_b,   // [10]
    float* __restrict__ out)           // [B,10]
{
    const int b = blockIdx.x;
    const int j = threadIdx.x;

    __shared__ float xs[I_SZ];
    __shared__ float gs[G_SZ];
    __shared__ float hc[2 * H_SZ];     // h_cat
    __shared__ float h1[64];
    __shared__ float h2[32];

    if (j < I_SZ) xs[j] = x_last[(size_t)b * I_SZ + j];
    if (j < H_SZ) hc[j] = h_fwd[b * H_SZ + j];
    __syncthreads();

    // reverse-cell gates (h0 = 0 -> no W_hh term)
    float acc = b_r[j];
#pragma unroll 8
    for (int k = 0; k < I_SZ; ++k) acc += xs[k] * W_ih_r[j * I_SZ + k];
    const int gate = j >> 6;
    float a;
    if (gate == 2) a = tanhf(acc);
    else           a = 1.0f / (1.0f + expf(-acc));
    gs[j] = a;
    __syncthreads();

    if (j < H_SZ) {
        const float c = gs[j] * gs[2 * H_SZ + j];     // i*g (c0 = 0)
        hc[H_SZ + j] = gs[3 * H_SZ + j] * tanhf(c);
    }
    __syncthreads();

    if (j < 64) {
        float s = fc1_b[j];
#pragma unroll 8
        for (int k = 0; k < 128; ++k) s += hc[k] * fc1_w[j * 128 + k];
        h1[j] = fmaxf(s, 0.0f);
    }
    __syncthreads();

    if (j < 32) {
        float s = fc2_b[j];
#pragma unroll 8
        for (int k = 0; k < 64; ++k) s += h1[k] * fc2_w[j * 64 + k];
        h2[j] = fmaxf(s, 0.0f);
    }
    __syncthreads();

    if (j < 10) {
        float s = fc3_b[j];
#pragma unroll
        for (int k = 0; k < 32; ++k) s += h2[k] * fc3_w[j * 32 + k];
        out[b * 10 + j] = s;
    }
}

extern "C" void kernel_launch(void* const* d_in, const int* in_sizes, int n_in,
                              void* d_out, int out_size, void* d_ws, size_t ws_size,
                              hipStream_t stream) {
    const float* x      = (const float*)d_in[0];
    const float* W_ih_f = (const float*)d_in[1];
    const float* W_hh_f = (const float*)d_in[2];
    const float* b_f    = (const float*)d_in[3];
    const float* W_ih_r = (const float*)d_in[4];
    // d_in[5] = W_hh_r : unused (zero initial state in reverse single step)
    const float* b_r    = (const float*)d_in[6];
    const float* fc1_w  = (const float*)d_in[7];
    const float* fc1_b  = (const float*)d_in[8];
    const float* fc2_w  = (const float*)d_in[9];
    const float* fc2_b  = (const float*)d_in[10];
    const float* fc3_w  = (const float*)d_in[11];
    const float* fc3_b  = (const float*)d_in[12];

    float* out   = (float*)d_out;
    float* h_fwd = (float*)d_ws;                  // [B,64] scratch

    const float* x_last = x + (size_t)(T_LEN - 1) * B_SZ * I_SZ;

    hipLaunchKernelGGL(lstm_fwd_scan, dim3(B_SZ), dim3(256), 0, stream,
                       x, W_ih_f, W_hh_f, b_f, h_fwd);
    hipLaunchKernelGGL(lstm_tail, dim3(B_SZ), dim3(256), 0, stream,
                       x_last, W_ih_r, b_r, h_fwd,
                       fc1_w, fc1_b, fc2_w, fc2_b, fc3_w, fc3_b, out);
}

// Round 2
// 1129.186 us; speedup vs baseline: 1.2275x; 1.2275x over previous
//
#include <hip/hip_runtime.h>
#include <math.h>

#define T_LEN 1024
#define B_SZ  256
#define I_SZ  128
#define H_SZ  64
#define G_SZ  256   // 4*H

typedef float f32x32 __attribute__((ext_vector_type(32)));

__device__ __forceinline__ float fast_sigmoid(float x) {
    float e = __expf(-x);
    return __builtin_amdgcn_rcpf(1.0f + e);
}
__device__ __forceinline__ float fast_tanh(float x) {
    float e = __expf(-2.0f * fabsf(x));
    float r = (1.0f - e) * __builtin_amdgcn_rcpf(1.0f + e);
    return copysignf(r, x);
}

// Load 32 consecutive floats from PTR into ext-vector V (registers, not alloca)
#define LD32(V, PTR)                                                        \
    { _Pragma("unroll") for (int q = 0; q < 8; ++q) {                       \
        float4 t_ = *reinterpret_cast<const float4*>((PTR) + 4 * q);        \
        V[4*q+0] = t_.x; V[4*q+1] = t_.y; V[4*q+2] = t_.z; V[4*q+3] = t_.w; } }

// acc += dot(ARR[BASE..BASE+7] (float4s), V[0..31]) with 4 independent chains
#define DOT8(V, ARR, BASE)                                                  \
    { _Pragma("unroll") for (int q = 0; q < 8; ++q) {                       \
        const float4 xv_ = (ARR)[(BASE) + q];                               \
        a0 = fmaf(xv_.x, V[4*q+0], a0);                                     \
        a1 = fmaf(xv_.y, V[4*q+1], a1);                                     \
        a2 = fmaf(xv_.z, V[4*q+2], a2);                                     \
        a3 = fmaf(xv_.w, V[4*q+3], a3); } }

// ---------------------------------------------------------------------------
// Forward LSTM scan: one block per batch element, 256 threads, thread j owns
// gate row j. Weights live in 6x f32x32 register vectors (192 VGPRs).
// ---------------------------------------------------------------------------
__global__ __launch_bounds__(256, 1) void lstm_fwd_scan(
    const float* __restrict__ x,      // [T,B,I]
    const float* __restrict__ W_ih,   // [256,128]
    const float* __restrict__ W_hh,   // [256,64]
    const float* __restrict__ bias,   // [256]
    float* __restrict__ h_out)        // [B,64]
{
    const int b = blockIdx.x;
    const int j = threadIdx.x;

    __shared__ float4 xs4[2][I_SZ / 4];   // x_t double buffer
    __shared__ float4 hs4[H_SZ / 4];      // h
    __shared__ float  gs[G_SZ];           // gate activations

    // ---- weights -> register vectors (SSA ext-vectors: cannot be alloca'd)
    f32x32 w0, w1, w2, w3, u0, u1;
    const float* wr = W_ih + j * I_SZ;
    LD32(w0, wr +  0) LD32(w1, wr + 32) LD32(w2, wr + 64) LD32(w3, wr + 96)
    const float* ur = W_hh + j * H_SZ;
    LD32(u0, ur +  0) LD32(u1, ur + 32)
    const float bj = bias[j];

    float c = 0.0f;
    if (j < H_SZ) reinterpret_cast<float*>(hs4)[j] = 0.0f;
    if (j < I_SZ) reinterpret_cast<float*>(xs4[0])[j] = x[(size_t)b * I_SZ + j];
    __syncthreads();

    // prefetch pointer for x[t+1]
    const float* xnp = x + (size_t)B_SZ * I_SZ + (size_t)b * I_SZ + j;
    const bool is_loader = (j < I_SZ);

    for (int t = 0; t < T_LEN; ++t) {
        const int cur = t & 1;
        const bool pf = is_loader & (t < T_LEN - 1);
        float xnext = 0.0f;
        if (pf) xnext = *xnp;                 // issue global load early

        // gate pre-activation with 4 independent FMA chains
        float a0 = bj, a1 = 0.0f, a2 = 0.0f, a3 = 0.0f;
        const float4* xc = xs4[cur];
        DOT8(w0, xc, 0) DOT8(w1, xc, 8) DOT8(w2, xc, 16) DOT8(w3, xc, 24)
        DOT8(u0, hs4, 0) DOT8(u1, hs4, 8)
        const float acc = (a0 + a1) + (a2 + a3);

        // activation (gate id wave-uniform: 64-lane waves, j>>6 constant/wave)
        const int gate = j >> 6;
        const float a = (gate == 2) ? fast_tanh(acc) : fast_sigmoid(acc);
        gs[j] = a;
        __syncthreads();

        // LDS write of prefetched x (vmcnt wait hidden under the dot above)
        if (pf) reinterpret_cast<float*>(xs4[cur ^ 1])[j] = xnext;

        if (j < H_SZ) {
            const float ig = gs[j];
            const float fg = gs[H_SZ + j];
            const float gg = gs[2 * H_SZ + j];
            const float og = gs[3 * H_SZ + j];
            c = fg * c + ig * gg;
            reinterpret_cast<float*>(hs4)[j] = og * fast_tanh(c);
        }
        __syncthreads();
        xnp += B_SZ * I_SZ;
    }

    if (j < H_SZ) h_out[b * H_SZ + j] = reinterpret_cast<float*>(hs4)[j];
}

// ---------------------------------------------------------------------------
// Reverse single cell (zero init state; W_hh_r drops out) + MLP head.
// ---------------------------------------------------------------------------
__global__ __launch_bounds__(256, 1) void lstm_tail(
    const float* __restrict__ x_last,  // [B,I]
    const float* __restrict__ W_ih_r,  // [256,128]
    const float* __restrict__ b_r,     // [256]
    const float* __restrict__ h_fwd,   // [B,64]
    const float* __restrict__ fc1_w,   // [64,128]
    const float* __restrict__ fc1_b,   // [64]
    const float* __restrict__ fc2_w,   // [32,64]
    const float* __restrict__ fc2_b,   // [32]
    const float* __restrict__ fc3_w,   // [10,32]
    const float* __restrict__ fc3_b,   // [10]
    float* __restrict__ out)           // [B,10]
{
    const int b = blockIdx.x;
    const int j = threadIdx.x;

    __shared__ float xs[I_SZ];
    __shared__ float gs[G_SZ];
    __shared__ float hc[2 * H_SZ];
    __shared__ float h1[64];
    __shared__ float h2[32];

    if (j < I_SZ) xs[j] = x_last[(size_t)b * I_SZ + j];
    if (j < H_SZ) hc[j] = h_fwd[b * H_SZ + j];
    __syncthreads();

    float a0 = b_r[j], a1 = 0.0f, a2 = 0.0f, a3 = 0.0f;
    const float* wrow = W_ih_r + j * I_SZ;
#pragma unroll
    for (int k = 0; k < I_SZ; k += 4) {
        float4 wv = *reinterpret_cast<const float4*>(wrow + k);
        a0 = fmaf(xs[k + 0], wv.x, a0);
        a1 = fmaf(xs[k + 1], wv.y, a1);
        a2 = fmaf(xs[k + 2], wv.z, a2);
        a3 = fmaf(xs[k + 3], wv.w, a3);
    }
    const float acc = (a0 + a1) + (a2 + a3);
    const int gate = j >> 6;
    gs[j] = (gate == 2) ? tanhf(acc) : 1.0f / (1.0f + expf(-acc));
    __syncthreads();

    if (j < H_SZ) {
        const float cc = gs[j] * gs[2 * H_SZ + j];     // i*g (c0 = 0)
        hc[H_SZ + j] = gs[3 * H_SZ + j] * tanhf(cc);
    }
    __syncthreads();

    if (j < 64) {
        float s0 = fc1_b[j], s1 = 0.0f, s2 = 0.0f, s3 = 0.0f;
        const float* w = fc1_w + j * 128;
#pragma unroll
        for (int k = 0; k < 128; k += 4) {
            float4 wv = *reinterpret_cast<const float4*>(w + k);
            s0 = fmaf(hc[k + 0], wv.x, s0);
            s1 = fmaf(hc[k + 1], wv.y, s1);
            s2 = fmaf(hc[k + 2], wv.z, s2);
            s3 = fmaf(hc[k + 3], wv.w, s3);
        }
        h1[j] = fmaxf((s0 + s1) + (s2 + s3), 0.0f);
    }
    __syncthreads();

    if (j < 32) {
        float s0 = fc2_b[j], s1 = 0.0f, s2 = 0.0f, s3 = 0.0f;
        const float* w = fc2_w + j * 64;
#pragma unroll
        for (int k = 0; k < 64; k += 4) {
            float4 wv = *reinterpret_cast<const float4*>(w + k);
            s0 = fmaf(h1[k + 0], wv.x, s0);
            s1 = fmaf(h1[k + 1], wv.y, s1);
            s2 = fmaf(h1[k + 2], wv.z, s2);
            s3 = fmaf(h1[k + 3], wv.w, s3);
        }
        h2[j] = fmaxf((s0 + s1) + (s2 + s3), 0.0f);
    }
    __syncthreads();

    if (j < 10) {
        float s = fc3_b[j];
#pragma unroll
        for (int k = 0; k < 32; ++k) s = fmaf(h2[k], fc3_w[j * 32 + k], s);
        out[b * 10 + j] = s;
    }
}

extern "C" void kernel_launch(void* const* d_in, const int* in_sizes, int n_in,
                              void* d_out, int out_size, void* d_ws, size_t ws_size,
                              hipStream_t stream) {
    const float* x      = (const float*)d_in[0];
    const float* W_ih_f = (const float*)d_in[1];
    const float* W_hh_f = (const float*)d_in[2];
    const float* b_f    = (const float*)d_in[3];
    const float* W_ih_r = (const float*)d_in[4];
    // d_in[5] = W_hh_r : unused (zero initial state in reverse single step)
    const float* b_r    = (const float*)d_in[6];
    const float* fc1_w  = (const float*)d_in[7];
    const float* fc1_b  = (const float*)d_in[8];
    const float* fc2_w  = (const float*)d_in[9];
    const float* fc2_b  = (const float*)d_in[10];
    const float* fc3_w  = (const float*)d_in[11];
    const float* fc3_b  = (const float*)d_in[12];

    float* out   = (float*)d_out;
    float* h_fwd = (float*)d_ws;                  // [B,64] scratch

    const float* x_last = x + (size_t)(T_LEN - 1) * B_SZ * I_SZ;

    hipLaunchKernelGGL(lstm_fwd_scan, dim3(B_SZ), dim3(256), 0, stream,
                       x, W_ih_f, W_hh_f, b_f, h_fwd);
    hipLaunchKernelGGL(lstm_tail, dim3(B_SZ), dim3(256), 0, stream,
                       x_last, W_ih_r, b_r, h_fwd,
                       fc1_w, fc1_b, fc2_w, fc2_b, fc3_w, fc3_b, out);
}